// Round 1
// baseline (2004.548 us; speedup 1.0000x reference)
//
#include <hip/hip_runtime.h>
#include <hip/hip_bf16.h>

// ---------------------------------------------------------------------------
// HybridCnnLnn R16: wave-local reduce + register-resident tables.
//  - remap lnn threads: h = tid&7 (i-octant), j = tid>>3 (unit).
//    The 8 octant partials for a unit are adjacent lanes -> 3x shfl_xor
//    butterfly replaces the psum-LDS round-trip + h==0 serial section.
//  - r12 (32 VGPR) and vw (16 VGPR) live in registers; prep pre-transposes
//    tables to [n][j*8+h] so reg-loads and the per-t S4 stream stay coalesced.
//  - vbuf ping-pong -> exactly 1 barrier per unfold (6/t vs ~15/t).
//  - all 64 timesteps of feats staged to LDS once (70KB, slot = i + (i>>4)
//    padding keeps the 8-way h-broadcast reads conflict-free).
// Arithmetic per element identical to R15; only cross-octant sum order
// changes (sequential -> butterfly), absmax ~1e-6 expected.
// ---------------------------------------------------------------------------

#define L2E 1.4426950408889634f

// ---------------- prep: fold params, transpose to [n][j*8+h] ---------------
__global__ __launch_bounds__(256)
void prep_kernel(const float* __restrict__ smu, const float* __restrict__ ssig,
                 const float* __restrict__ sW,  const float* __restrict__ serev,
                 const float* __restrict__ mu,  const float* __restrict__ sig,
                 const float* __restrict__ W,   const float* __restrict__ erev,
                 const float* __restrict__ in_w, const float* __restrict__ in_b,
                 float2* __restrict__ R12T, float* __restrict__ VTT,
                 float4* __restrict__ S4T) {
  int idx = blockIdx.x * 256 + threadIdx.x;      // idx = i*128 + j
  int i = idx >> 7, j = idx & 127;
  int h = i >> 4, n = i & 15;
  int dst = n * 1024 + j * 8 + h;                // lane-major for lnn mapping
  float r1 = sig[idx] * L2E;
  R12T[dst] = make_float2(r1, mu[idx] * r1);     // arg = r2 - r1*v
  VTT[dst]  = W[idx] * erev[idx];                // |erev|=1 -> |VT| = W
  float ss = ssig[idx] * L2E;
  S4T[dst] = make_float4(ss * in_w[i], (smu[idx] - in_b[i]) * ss,
                         sW[idx] * serev[idx], 0.f);
}

// ----------------------------- conv1 (k=5, tiled) --------------------------
// x [512,256,24] -> P1 [512,64,128] ([b][co][t']), relu+maxpool2 fused
__launch_bounds__(512)
__global__ void conv1_kernel(const float* __restrict__ x, const float* __restrict__ w1,
                             const float* __restrict__ b1, float* __restrict__ P1) {
  __shared__ float xs[6240];                     // rows t in [-2,258), 24 ch
  int tid = threadIdx.x, b = blockIdx.x;
  const float* xb = x + (size_t)b * 6144;
  for (int idx = tid; idx < 6144; idx += 512) xs[idx + 48] = xb[idx];
  if (tid < 48) { xs[tid] = 0.f; xs[6192 + tid] = 0.f; }
  __syncthreads();
  int tp = tid & 127, cq = tid >> 7;             // 128 pooled t x 4 co-quarters
  float acc0[16], acc1[16];
#pragma unroll
  for (int n = 0; n < 16; n++) { float bb = b1[cq * 16 + n]; acc0[n] = bb; acc1[n] = bb; }
  for (int cic = 0; cic < 3; cic++) {            // ci chunks of 8
    float p[6][8];
#pragma unroll
    for (int r = 0; r < 6; r++) {
      const float* row = &xs[(2 * tp + r) * 24 + cic * 8];
      float4 a = *(const float4*)row;
      float4 c = *(const float4*)(row + 4);
      p[r][0] = a.x; p[r][1] = a.y; p[r][2] = a.z; p[r][3] = a.w;
      p[r][4] = c.x; p[r][5] = c.y; p[r][6] = c.z; p[r][7] = c.w;
    }
#pragma unroll
    for (int n = 0; n < 16; n++) {
      const float* wr = w1 + (cq * 16 + n) * 120 + cic * 40;  // uniform -> s_load
#pragma unroll
      for (int c = 0; c < 8; c++) {
#pragma unroll
        for (int kk = 0; kk < 5; kk++) {
          float w = wr[c * 5 + kk];
          acc0[n] = fmaf(p[kk][c],     w, acc0[n]);
          acc1[n] = fmaf(p[kk + 1][c], w, acc1[n]);
        }
      }
    }
  }
  float* pb = P1 + (size_t)b * 8192;
#pragma unroll
  for (int n = 0; n < 16; n++)
    pb[(cq * 16 + n) * 128 + tp] = fmaxf(fmaxf(acc0[n], acc1[n]), 0.f);
}

// ----------------------------- conv2 (k=3, tiled) --------------------------
// P1 [512,64,128] -> feats [512,64,128] laid out [b][t'][co]
__launch_bounds__(512)
__global__ void conv2_kernel(const float* __restrict__ P1, const float* __restrict__ w2,
                             const float* __restrict__ b2, float* __restrict__ feats) {
  __shared__ float xs[8450];                     // [t+1][ci], stride 65
  int tid = threadIdx.x, b = blockIdx.x;
  const float* pb = P1 + (size_t)b * 8192;
  for (int idx = tid; idx < 8192; idx += 512) {
    int ci = idx >> 7, t = idx & 127;
    xs[(t + 1) * 65 + ci] = pb[idx];
  }
  if (tid < 65) { xs[tid] = 0.f; xs[129 * 65 + tid] = 0.f; }
  __syncthreads();
  int tp = tid & 63, cq = tid >> 6;              // 64 pooled t x 8 co-octants
  float acc0[16], acc1[16];
#pragma unroll
  for (int n = 0; n < 16; n++) { float bb = b2[cq * 16 + n]; acc0[n] = bb; acc1[n] = bb; }
  for (int cic = 0; cic < 8; cic++) {            // ci chunks of 8
    float p[4][8];
#pragma unroll
    for (int r = 0; r < 4; r++)
#pragma unroll
      for (int c = 0; c < 8; c++)
        p[r][c] = xs[(2 * tp + r) * 65 + cic * 8 + c];
#pragma unroll
    for (int n = 0; n < 16; n++) {
      const float* wr = w2 + (cq * 16 + n) * 192 + cic * 24;  // native [co][ci][kk]
#pragma unroll
      for (int c = 0; c < 8; c++) {
#pragma unroll
        for (int kk = 0; kk < 3; kk++) {
          float w = wr[c * 3 + kk];
          acc0[n] = fmaf(p[kk][c],     w, acc0[n]);
          acc1[n] = fmaf(p[kk + 1][c], w, acc1[n]);
        }
      }
    }
  }
  __syncthreads();                               // reuse xs as [tp][co]
#pragma unroll
  for (int n = 0; n < 16; n += 4) {
    float4 v;
    v.x = fmaxf(fmaxf(acc0[n],     acc1[n]),     0.f);
    v.y = fmaxf(fmaxf(acc0[n + 1], acc1[n + 1]), 0.f);
    v.z = fmaxf(fmaxf(acc0[n + 2], acc1[n + 2]), 0.f);
    v.w = fmaxf(fmaxf(acc0[n + 3], acc1[n + 3]), 0.f);
    *(float4*)&xs[tp * 128 + cq * 16 + n] = v;
  }
  __syncthreads();
  float* fb = feats + (size_t)b * 8192;
  for (int idx = tid; idx < 8192; idx += 512) fb[idx] = xs[idx];
}

// --------------------------- LTC recurrence + head -------------------------
// block = 1024: h = tid&7 (i-octant), j = tid>>3 (unit). 2 batches/block,
// grid 256 = 1 block/CU. r12+vw in 48 VGPRs; feats staged to LDS once;
// per-unfold: 16 reg-iters -> 3x shfl_xor butterfly -> leader update ->
// ping-pong vbuf write -> ONE barrier.
__launch_bounds__(1024)
__global__ void lnn_kernel(const float2* __restrict__ R12T, const float* __restrict__ VTT,
                           const float4* __restrict__ S4T,
                           const float* __restrict__ feats,
                           const float* __restrict__ cm_t, const float* __restrict__ gleak,
                           const float* __restrict__ vleak,
                           const float* __restrict__ fc1_w, const float* __restrict__ fc1_b,
                           const float* __restrict__ fc2_w, const float* __restrict__ fc2_b,
                           float* __restrict__ out) {
  __shared__ float2 xt_all[64][136];             // [t][slot(i)] (b0,b1), 69.6KB
  __shared__ float2 vbuf[2][136];                // ping-pong v, padded slots
  __shared__ float red[2][64];
  int tid = threadIdx.x;
  int h = tid & 7, j = tid >> 3;
  int b0 = blockIdx.x * 2;

  // stage all 64 timesteps for both batches (coalesced reads, slotted writes)
  {
    const float* f0 = feats + (size_t)b0 * 8192;
    const float* f1 = feats + (size_t)(b0 + 1) * 8192;
    for (int idx = tid; idx < 8192; idx += 1024) {
      int t = idx >> 7, u = idx & 127;
      xt_all[t][u + (u >> 4)] = make_float2(f0[idx], f1[idx]);
    }
  }

  // tables -> registers (coalesced: [n][tid] layout from prep)
  float2 r12[16]; float vw[16];
#pragma unroll
  for (int n = 0; n < 16; n++) {
    r12[n] = R12T[n * 1024 + tid];
    vw[n]  = VTT[n * 1024 + tid];
  }

  float cmj = cm_t[j], glk = gleak[j];
  float gvl = glk * vleak[j], cgl = cmj + glk;
  float vj0 = 0.f, vj1 = 0.f;
  if (tid < 136) vbuf[0][tid] = make_float2(0.f, 0.f);
  __syncthreads();

  const float4* sp = S4T + tid;
  const int hb = 17 * h;                         // slot base: 16h + n + h

  for (int t = 0; t < 64; t++) {
    // ---- sensory partials (per-thread slice; merged into unfold reduce) ----
    float sn0 = 0.f, sd0 = 0.f, sn1 = 0.f, sd1 = 0.f;
#pragma unroll 8
    for (int n = 0; n < 16; n++) {
      float4 s = sp[n * 1024];
      float2 xv = xt_all[t][hb + n];
      float q0 = __builtin_amdgcn_rcpf(1.f + __builtin_amdgcn_exp2f(fmaf(-s.x, xv.x, s.y)));
      sn0 = fmaf(s.z, q0, sn0); sd0 = fmaf(fabsf(s.z), q0, sd0);
      float q1 = __builtin_amdgcn_rcpf(1.f + __builtin_amdgcn_exp2f(fmaf(-s.x, xv.y, s.y)));
      sn1 = fmaf(s.z, q1, sn1); sd1 = fmaf(fabsf(s.z), q1, sd1);
    }

    // ---- 6 semi-implicit ODE unfolds ----
#pragma unroll
    for (int u = 0; u < 6; u++) {
      float n0 = sn0, d0 = sd0, n1 = sn1, d1 = sd1;
      const float2* vb = &vbuf[u & 1][hb];
#pragma unroll
      for (int n = 0; n < 16; n++) {
        float2 rr = r12[n];
        float2 v2 = vb[n];                       // conflict-free 8-way broadcast
        float q0 = __builtin_amdgcn_rcpf(1.f + __builtin_amdgcn_exp2f(fmaf(-rr.x, v2.x, rr.y)));
        n0 = fmaf(vw[n], q0, n0); d0 = fmaf(fabsf(vw[n]), q0, d0);
        float q1 = __builtin_amdgcn_rcpf(1.f + __builtin_amdgcn_exp2f(fmaf(-rr.x, v2.y, rr.y)));
        n1 = fmaf(vw[n], q1, n1); d1 = fmaf(fabsf(vw[n]), q1, d1);
      }
      // butterfly reduce over the 8 octant lanes (adjacent lanes)
#pragma unroll
      for (int m = 1; m < 8; m <<= 1) {
        n0 += __shfl_xor(n0, m, 64);
        d0 += __shfl_xor(d0, m, 64);
        n1 += __shfl_xor(n1, m, 64);
        d1 += __shfl_xor(d1, m, 64);
      }
      if (h == 0) {                              // leader lane per unit
        float den0 = cgl + d0, den1 = cgl + d1;
        float i0 = __builtin_amdgcn_rcpf(den0); i0 = i0 * fmaf(-den0, i0, 2.f);
        float i1 = __builtin_amdgcn_rcpf(den1); i1 = i1 * fmaf(-den1, i1, 2.f);
        vj0 = (fmaf(cmj, vj0, gvl) + n0) * i0;
        vj1 = (fmaf(cmj, vj1, gvl) + n1) * i1;
        vbuf[(u + 1) & 1][j + (j >> 4)] = make_float2(vj0, vj1);
      }
      __syncthreads();                           // the ONLY barrier per unfold
    }
  }

  // ---- MLP head (final v sits in vbuf[0] after 6 flips) ----
  if (tid < 128) {
    int g = tid >> 6, d = tid & 63;
    float acc = fc1_b[d];
    for (int u = 0; u < 128; u++) {
      float2 v2 = vbuf[0][u + (u >> 4)];
      acc = fmaf(g ? v2.y : v2.x, fc1_w[d * 128 + u], acc);
    }
    red[g][d] = fmaxf(acc, 0.f) * fc2_w[d];
  }
  __syncthreads();
  if (tid < 2) {
    float s = fc2_b[0];
    for (int d = 0; d < 64; d++) s += red[tid][d];
    out[b0 + tid] = s;
  }
}

// ------------------------------- launcher ----------------------------------
extern "C" void kernel_launch(void* const* d_in, const int* in_sizes, int n_in,
                              void* d_out, int out_size, void* d_ws, size_t ws_size,
                              hipStream_t stream) {
  (void)in_sizes; (void)n_in; (void)out_size; (void)ws_size;
  char* ws = (char*)d_ws;
  // 32MB envelope, time-multiplexed:
  //   P1 [0,16M) live conv1->conv2; tables [0,448K) after conv2 (prep);
  //   feats [16M,32M) live conv2->lnn.
  float*  P1   = (float*)(ws);
  float*  feats= (float*)(ws + (16 << 20));
  float2* R12T = (float2*)(ws + 0);             // 128KB
  float*  VTT  = (float*)(ws + (128 << 10));    // 64KB
  float4* S4T  = (float4*)(ws + (192 << 10));   // 256KB -> ends 448KB

  conv1_kernel<<<512, 512, 0, stream>>>((const float*)d_in[0],
      (const float*)d_in[1], (const float*)d_in[2], P1);
  conv2_kernel<<<512, 512, 0, stream>>>(P1,
      (const float*)d_in[3], (const float*)d_in[4], feats);
  prep_kernel<<<64, 256, 0, stream>>>(
      (const float*)d_in[7], (const float*)d_in[8],
      (const float*)d_in[9], (const float*)d_in[10],
      (const float*)d_in[11], (const float*)d_in[12],
      (const float*)d_in[13], (const float*)d_in[14],
      (const float*)d_in[5], (const float*)d_in[6],
      R12T, VTT, S4T);
  lnn_kernel<<<256, 1024, 0, stream>>>(R12T, VTT, S4T, feats,
      (const float*)d_in[17], (const float*)d_in[16], (const float*)d_in[15],
      (const float*)d_in[18], (const float*)d_in[19],
      (const float*)d_in[20], (const float*)d_in[21],
      (float*)d_out);
}